// Round 9
// baseline (629.915 us; speedup 1.0000x reference)
//
#include <hip/hip_runtime.h>
#include <hip/hip_bf16.h>

#define M_DIM 4096
#define N_DIM 8192
#define K_DIM 8192
#define CAP   768          // bin capacity per W row (mean 488, sigma 22)
#define OVF_CAP 4096

using bf16x8 = __attribute__((ext_vector_type(8))) short;
using f32x4  = __attribute__((ext_vector_type(4))) float;
using v2s    = __attribute__((ext_vector_type(2))) short;

static __device__ __forceinline__ unsigned short f32_to_bf16_rne(float f) {
    unsigned u = __float_as_uint(f);
    unsigned rounding = 0x7FFFu + ((u >> 16) & 1u);
    u += rounding;
    return (unsigned short)(u >> 16);
}

// atomically add bf16 h into W[idx] (overflow path only; ~0 items in practice)
static __device__ __forceinline__ void atomic_add_bf16(unsigned short* W,
                                                       unsigned idx,
                                                       unsigned short h) {
    unsigned* p = (unsigned*)W + (idx >> 1);
    const int hi = (int)(idx & 1);
#if __has_builtin(__builtin_amdgcn_global_atomic_fadd_v2bf16)
    v2s pk;
    pk[0] = hi ? (short)0 : (short)h;
    pk[1] = hi ? (short)h : (short)0;
    __builtin_amdgcn_global_atomic_fadd_v2bf16(
        (__attribute__((address_space(1))) v2s*)p, pk);
#else
    float vf = __uint_as_float(((unsigned)h) << 16);
    unsigned old = __hip_atomic_load(p, __ATOMIC_RELAXED, __HIP_MEMORY_SCOPE_AGENT);
    while (true) {
        unsigned cur = old;
        unsigned short th = hi ? (unsigned short)(cur >> 16)
                               : (unsigned short)(cur & 0xffffu);
        float f = __uint_as_float(((unsigned)th) << 16) + vf;
        unsigned short nh = f32_to_bf16_rne(f);
        unsigned nw = hi ? ((cur & 0x0000ffffu) | ((unsigned)nh << 16))
                         : ((cur & 0xffff0000u) | (unsigned)nh);
        unsigned prev = atomicCAS(p, cur, nw);
        if (prev == cur) break;
        old = prev;
    }
#endif
}

// ---------------- zero (16B granules) ----------------
__global__ void zero_kernel(float4* __restrict__ p, int n4) {
    int i = blockIdx.x * blockDim.x + threadIdx.x;
    int stride = gridDim.x * blockDim.x;
    float4 z = make_float4(0.f, 0.f, 0.f, 0.f);
    for (; i < n4; i += stride) p[i] = z;
}

// ---------------- pass 1: bin items by destination row ----------------
// bins[row][pos] = (col<<16) | bf16(val).  pos via atomicAdd on fill[row]
// (8192 hot L2-resident counters).  2 items/thread with int2/float2 loads
// (r8: halves instruction count, doubles MLP on the atomic chain).
__global__ void reorder_kernel(const float* __restrict__ vals,
                               const int* __restrict__ rows,
                               const int* __restrict__ cols,
                               unsigned* __restrict__ bins,
                               unsigned* __restrict__ fill,
                               unsigned* __restrict__ ovf_cnt,
                               uint2* __restrict__ ovf, int n) {
    int i = (blockIdx.x * blockDim.x + threadIdx.x) * 2;
    if (i >= n) return;
    const int m = (i + 2 <= n) ? 2 : 1;
    int2   r2 = *(const int2*)(rows + i);
    int2   c2 = *(const int2*)(cols + i);
    float2 v2 = *(const float2*)(vals + i);
    #pragma unroll
    for (int j = 0; j < 2; ++j) {
        if (j >= m) break;
        int r = j ? r2.y : r2.x;
        int c = j ? c2.y : c2.x;
        unsigned h = f32_to_bf16_rne(j ? v2.y : v2.x);
        unsigned pos = atomicAdd(&fill[r], 1u);
        if (pos < CAP) {
            bins[(size_t)r * CAP + pos] = ((unsigned)c << 16) | h;
        } else {
            unsigned o = atomicAdd(ovf_cnt, 1u);
            if (o < OVF_CAP)
                ovf[o] = make_uint2((unsigned)r * K_DIM + (unsigned)c, h);
        }
    }
}

// ---------------- pass 2: per-row accumulate + write full bf16 row --------
// One block per W row: f32 LDS rowbuf (32 KB), LDS atomics for ~488 items,
// then one coalesced 16 KB row write.  Replaces BOTH the W-zero pass and
// the global atomic scatter; duplicates summed in f32 before one rounding.
__global__ __launch_bounds__(256) void row_accum_kernel(
        const unsigned* __restrict__ bins,
        const unsigned* __restrict__ fill,
        unsigned short* __restrict__ W) {
    __shared__ float rowbuf[K_DIM];    // 32 KB
    const int row = blockIdx.x;
    const int tid = threadIdx.x;
    float4* rb4 = (float4*)rowbuf;
    #pragma unroll
    for (int i = 0; i < K_DIM / 4 / 256; ++i)
        rb4[i * 256 + tid] = make_float4(0.f, 0.f, 0.f, 0.f);
    __syncthreads();
    int n = (int)fill[row];
    if (n > CAP) n = CAP;
    const unsigned* seg = bins + (size_t)row * CAP;
    for (int i = tid; i < n; i += 256) {
        unsigned u = seg[i];
        atomicAdd(&rowbuf[u >> 16], __uint_as_float((u & 0xffffu) << 16));
    }
    __syncthreads();
    unsigned* Wrow = (unsigned*)(W + (size_t)row * K_DIM);  // 4096 dwords
    #pragma unroll
    for (int i = 0; i < K_DIM / 2 / 256; ++i) {
        int j = i * 256 + tid;
        unsigned pa = f32_to_bf16_rne(rowbuf[2 * j]);
        unsigned pb = f32_to_bf16_rne(rowbuf[2 * j + 1]);
        Wrow[j] = pa | (pb << 16);
    }
}

// ---------------- pass 3: apply (rare) overflow items ----------------
__global__ void ovf_apply_kernel(const unsigned* __restrict__ ovf_cnt,
                                 const uint2* __restrict__ ovf,
                                 unsigned short* __restrict__ W) {
    unsigned n = *ovf_cnt;
    if (n > OVF_CAP) n = OVF_CAP;
    for (unsigned i = threadIdx.x; i < n; i += blockDim.x)
        atomic_add_bf16(W, ovf[i].x, (unsigned short)ovf[i].y);
}

// ---------------- f32 -> bf16 cast (x only) ----------------
__global__ void cvt_bf16_kernel(const float4* __restrict__ src,
                                ushort4* __restrict__ dst, int n4) {
    int i = blockIdx.x * blockDim.x + threadIdx.x;
    int stride = gridDim.x * blockDim.x;
    for (; i < n4; i += stride) {
        float4 v = src[i];
        ushort4 o;
        o.x = f32_to_bf16_rne(v.x);
        o.y = f32_to_bf16_rne(v.y);
        o.z = f32_to_bf16_rne(v.z);
        o.w = f32_to_bf16_rne(v.w);
        dst[i] = o;
    }
}

// ---------------- zero d_out fallback (ws too small diagnostic) ----------------
__global__ void zero_out_kernel(float* __restrict__ p, int n) {
    int i = blockIdx.x * blockDim.x + threadIdx.x;
    int stride = gridDim.x * blockDim.x;
    for (; i < n; i += stride) p[i] = 0.f;
}

// ---------------- bf16 NT GEMM, 256x256 8-phase (T2+T3+T4+T5) ----------------
// r8 change: phase = (ksub, m-half) instead of (C-quadrant).  r6's q0 issued
// 12 b128/wave (all 8 B frags + 4 A) = ~1150 cyc LDS vs 620 cyc MFMA per CU
// -> LDS-bound bulge.  New split: ph0 {4 B(ks0) + 4 A}, ph1 {4 A},
// ph2 {4 B(ks1) + 4 A}, ph3 {4 A} -> max 768 cyc/phase.  16 MFMA per phase
// (acc[mh*4+m][n], all independent).  B[db] is now read at ph2, so B(t+2)
// staging moves wholly to ph3: ph2's reads complete before that wave's
// lgkmcnt(0) which precedes BARRIER_B(ph2), which precedes every wave's ph3
// stage issue -> no overwrite-before-read.  vmcnt ledger unchanged:
//   ph0: A(t+1) h0 -> db^1   ph1: A(t+1) h1 -> db^1
//   ph3: B(t+2) h0+h1 -> db
// boundary vmcnt(4) drains A(t+1), leaves B(t+2)'s 4 loads in flight (T4).
// LDS swizzle (T2, rule #21): slot (row,c) holds global k-chunk c^(row&7);
// staging pre-swizzles the global source, reads apply the same involution.
__global__ __launch_bounds__(512, 2) void gemm_bt(const ushort* __restrict__ A,
                                                  const ushort* __restrict__ B,
                                                  float* __restrict__ C) {
    constexpr int BK = 64;
    constexpr int NT = K_DIM / BK;     // 128 K-tiles
    __shared__ ushort lds[65536];      // 128 KiB

    const int nbn = N_DIM / 256;       // 32
    const int bm = blockIdx.x / nbn;
    const int bn = blockIdx.x % nbn;
    const int brow = bm * 256, bcol = bn * 256;

    const int t    = threadIdx.x;
    const int lane = t & 63;
    const int wid  = t >> 6;           // 0..7
    const int wm   = wid >> 2;         // 0..1 (M)
    const int wn   = wid & 3;          // 0..3 (N)
    const int lrow = lane & 15;
    const int ghi  = lane >> 4;        // 0..3

    const int c0 = (0 + ghi) ^ (lrow & 7);   // ksub 0
    const int c1 = (4 + ghi) ^ (lrow & 7);   // ksub 1

    f32x4 acc[8][4] = {};

    auto stage_half = [&](int db, int op, int half, int ktile) {
        const ushort* G = (op == 0) ? A : B;
        const int rbase = ((op == 0) ? brow : bcol) + half * 128;
        #pragma unroll
        for (int i = 0; i < 2; ++i) {
            int fl  = i * 512 + t;                 // 0..1023
            int row = fl >> 3;
            int cc  = (fl & 7) ^ (row & 7);
            const ushort* src = G + (size_t)(rbase + row) * K_DIM + ktile * BK + cc * 8;
            __builtin_amdgcn_global_load_lds(
                (const __attribute__((address_space(1))) void*)src,
                (__attribute__((address_space(3))) void*)
                    (&lds[db * 32768 + op * 16384 + half * 8192 + fl * 8]),
                16, 0, 0);
        }
    };

    auto tile_body = [&](int tt, int db, bool stgA, bool stgB, int vm) {
        const ushort* Ah = &lds[db * 32768 + wm * 8192];
        const ushort* Bh = &lds[db * 32768 + 16384 + (wn >> 1) * 8192 + (wn & 1) * 4096];
        const ushort* a0 = Ah + lrow * 64 + c0 * 8;
        const ushort* a1 = Ah + lrow * 64 + c1 * 8;
        const ushort* b0 = Bh + lrow * 64 + c0 * 8;
        const ushort* b1 = Bh + lrow * 64 + c1 * 8;
        bf16x8 bfr[4];                 // current-ksub B frags (2-phase resident)
        #pragma unroll
        for (int ph = 0; ph < 4; ++ph) {
            const int ks = ph >> 1;    // 0,0,1,1
            const int mh = ph & 1;     // 0,1,0,1
            const ushort* ab = ks ? a1 : a0;
            bf16x8 af[4];
            if (mh == 0) {
                const ushort* bb = ks ? b1 : b0;
                #pragma unroll
                for (int n = 0; n < 4; ++n)
                    bfr[n] = *(const bf16x8*)(bb + n * 1024);
            }
            #pragma unroll
            for (int m = 0; m < 4; ++m)
                af[m] = *(const bf16x8*)(ab + (mh * 4 + m) * 1024);

            if (ph == 0 && stgA) stage_half(db ^ 1, 0, 0, tt + 1);
            if (ph == 1 && stgA) stage_half(db ^ 1, 0, 1, tt + 1);
            if (ph == 3 && stgB) {
                stage_half(db, 1, 0, tt + 2);
                stage_half(db, 1, 1, tt + 2);
            }
            __builtin_amdgcn_s_barrier();
            asm volatile("s_waitcnt lgkmcnt(0)" ::: "memory");
            __builtin_amdgcn_s_setprio(1);
            #pragma unroll
            for (int m = 0; m < 4; ++m)
                #pragma unroll
                for (int n = 0; n < 4; ++n)
                    acc[mh * 4 + m][n] = __builtin_amdgcn_mfma_f32_16x16x32_bf16(
                        af[m], bfr[n], acc[mh * 4 + m][n], 0, 0, 0);
            __builtin_amdgcn_s_setprio(0);
            if (ph == 3) {
                if (vm == 4) asm volatile("s_waitcnt vmcnt(4)" ::: "memory");
                else         asm volatile("s_waitcnt vmcnt(0)" ::: "memory");
            }
            __builtin_amdgcn_s_barrier();
        }
    };

    // ---- prologue: tile 0 fully + B(1); drain to 4 (B(1) stays in flight) ----
    stage_half(0, 0, 0, 0);
    stage_half(0, 0, 1, 0);
    stage_half(0, 1, 0, 0);
    stage_half(0, 1, 1, 0);
    stage_half(1, 1, 0, 1);
    stage_half(1, 1, 1, 1);
    asm volatile("s_waitcnt vmcnt(4)" ::: "memory");
    __builtin_amdgcn_s_barrier();

    for (int tt = 0; tt < NT - 2; tt += 2) {
        tile_body(tt,     0, true, true, 4);
        tile_body(tt + 1, 1, true, true, 4);
    }
    tile_body(NT - 2, 0, true,  false, 0);
    tile_body(NT - 1, 1, false, false, 0);

    // ---- epilogue: C/D layout col=lane&15, row=(lane>>4)*4+r ----
    const int crow0 = brow + wm * 128;
    const int ccol0 = bcol + wn * 64;
    #pragma unroll
    for (int m = 0; m < 8; ++m) {
        #pragma unroll
        for (int n = 0; n < 4; ++n) {
            int col   = ccol0 + n * 16 + lrow;
            int rbase = crow0 + m * 16 + (lane >> 4) * 4;
            #pragma unroll
            for (int r = 0; r < 4; ++r)
                C[(size_t)(rbase + r) * N_DIM + col] = acc[m][n][r];
        }
    }
}

extern "C" void kernel_launch(void* const* d_in, const int* in_sizes, int n_in,
                              void* d_out, int out_size, void* d_ws, size_t ws_size,
                              hipStream_t stream) {
    const float* x    = (const float*)d_in[0];
    const float* vals = (const float*)d_in[1];
    const int* rows   = (const int*)d_in[2];
    const int* cols   = (const int*)d_in[3];
    float* out        = (float*)d_out;
    const int n_items = in_sizes[1];

    const size_t W_BF16_BYTES = (size_t)N_DIM * K_DIM * 2;        // 128 MiB
    const size_t X_BF16_BYTES = (size_t)M_DIM * K_DIM * 2;        //  64 MiB
    const size_t BINS_BYTES   = (size_t)N_DIM * CAP * 4;          //  24 MiB
    const size_t FILL_BYTES   = (size_t)N_DIM * 4;                //  32 KiB
    const size_t OVF_BYTES    = 16 + (size_t)OVF_CAP * 8;
    const size_t NEEDED = W_BF16_BYTES + X_BF16_BYTES + BINS_BYTES
                        + FILL_BYTES + OVF_BYTES;

    if (ws_size < NEEDED) {
        // Diagnostic fallback: clean absmax=126 failure signals ws too small.
        zero_out_kernel<<<2048, 256, 0, stream>>>(out, out_size);
        return;
    }

    char* ws = (char*)d_ws;
    unsigned short* Wb = (unsigned short*)ws;
    ushort*   Xb      = (ushort*)(ws + W_BF16_BYTES);
    unsigned* bins    = (unsigned*)(ws + W_BF16_BYTES + X_BF16_BYTES);
    unsigned* fill    = (unsigned*)(ws + W_BF16_BYTES + X_BF16_BYTES + BINS_BYTES);
    unsigned* ovf_cnt = fill + N_DIM;
    uint2*    ovf     = (uint2*)(ovf_cnt + 4);

    // 1) zero fill counters + ovf_cnt (32 KiB + 16 B; re-zeroed every call)
    zero_kernel<<<32, 256, 0, stream>>>((float4*)fill,
                                        (int)((FILL_BYTES + 16) / 16));
    // 2) bin items by destination row (packed (col<<16)|bf16(val))
    reorder_kernel<<<(n_items / 2 + 255) / 256, 256, 0, stream>>>(
        vals, rows, cols, bins, fill, ovf_cnt, ovf, n_items);
    // 3) per-row accumulate in f32 LDS + write full bf16 W (no W-zero pass)
    row_accum_kernel<<<N_DIM, 256, 0, stream>>>(bins, fill, Wb);
    // 4) apply overflow items (normally zero)
    ovf_apply_kernel<<<1, 256, 0, stream>>>(ovf_cnt, ovf, Wb);
    // 5) cast x to bf16
    cvt_bf16_kernel<<<2048, 256, 0, stream>>>((const float4*)x, (ushort4*)Xb,
                                              (M_DIM * K_DIM) / 4);
    // 6) GEMM: out = Xb (M x K) * Wb (N x K)^T
    gemm_bt<<<(M_DIM / 256) * (N_DIM / 256), 512, 0, stream>>>(
        Xb, (const ushort*)Wb, out);
}

// Round 10
// 591.219 us; speedup vs baseline: 1.0655x; 1.0655x over previous
//
#include <hip/hip_runtime.h>
#include <hip/hip_bf16.h>

#define M_DIM 4096
#define N_DIM 8192
#define K_DIM 8192
#define CAP   768          // bin capacity per W row (mean 488, sigma 22)
#define OVF_CAP 4096
#define CVT_BLOCKS 2048

using bf16x8 = __attribute__((ext_vector_type(8))) short;
using f32x4  = __attribute__((ext_vector_type(4))) float;

static __device__ __forceinline__ unsigned short f32_to_bf16_rne(float f) {
    unsigned u = __float_as_uint(f);
    unsigned rounding = 0x7FFFu + ((u >> 16) & 1u);
    u += rounding;
    return (unsigned short)(u >> 16);
}

// ---------------- fused pass 1: cvt x -> bf16  ||  bin items by row -------
// Blocks [0, CVT_BLOCKS) grid-stride the x cast (pure BW); remaining blocks
// bin 2 items/thread: bins[row][pos] = (col<<16)|bf16(val), pos via
// atomicAdd on fill[row] (8192 hot L2 counters).  The cast work fills the
// atomic-latency bubbles of the binning blocks (co-resident on the CUs).
// Overflow (>=13 sigma, ~impossible) goes to a list merged by row_accum.
__global__ void cvt_reorder_kernel(const float4* __restrict__ xsrc,
                                   ushort4* __restrict__ xdst, int xn4,
                                   const float* __restrict__ vals,
                                   const int* __restrict__ rows,
                                   const int* __restrict__ cols,
                                   unsigned* __restrict__ bins,
                                   unsigned* __restrict__ fill,
                                   unsigned* __restrict__ ovf_cnt,
                                   uint2* __restrict__ ovf, int n) {
    if (blockIdx.x < CVT_BLOCKS) {
        int i = blockIdx.x * blockDim.x + threadIdx.x;
        int stride = CVT_BLOCKS * blockDim.x;
        for (; i < xn4; i += stride) {
            float4 v = xsrc[i];
            ushort4 o;
            o.x = f32_to_bf16_rne(v.x);
            o.y = f32_to_bf16_rne(v.y);
            o.z = f32_to_bf16_rne(v.z);
            o.w = f32_to_bf16_rne(v.w);
            xdst[i] = o;
        }
        return;
    }
    int i = ((blockIdx.x - CVT_BLOCKS) * blockDim.x + threadIdx.x) * 2;
    if (i >= n) return;
    const int m = (i + 2 <= n) ? 2 : 1;
    int2   r2 = *(const int2*)(rows + i);
    int2   c2 = *(const int2*)(cols + i);
    float2 v2 = *(const float2*)(vals + i);
    #pragma unroll
    for (int j = 0; j < 2; ++j) {
        if (j >= m) break;
        int r = j ? r2.y : r2.x;
        int c = j ? c2.y : c2.x;
        unsigned h = f32_to_bf16_rne(j ? v2.y : v2.x);
        unsigned pos = atomicAdd(&fill[r], 1u);
        if (pos < CAP) {
            bins[(size_t)r * CAP + pos] = ((unsigned)c << 16) | h;
        } else {
            unsigned o = atomicAdd(ovf_cnt, 1u);
            if (o < OVF_CAP)
                ovf[o] = make_uint2((unsigned)r * K_DIM + (unsigned)c, h);
        }
    }
}

// ---------------- pass 2: per-row accumulate + write full bf16 row --------
// One block per W row: f32 LDS rowbuf (32 KB), LDS atomics for ~488 items,
// merge any overflow entries for this row (f32, pre-rounding), then one
// coalesced 16 KB row write.  Replaces the W-zero pass, the global atomic
// scatter, AND the separate ovf_apply launch.
__global__ __launch_bounds__(256) void row_accum_kernel(
        const unsigned* __restrict__ bins,
        const unsigned* __restrict__ fill,
        const unsigned* __restrict__ ovf_cnt,
        const uint2* __restrict__ ovf,
        unsigned short* __restrict__ W) {
    __shared__ float rowbuf[K_DIM];    // 32 KB
    const int row = blockIdx.x;
    const int tid = threadIdx.x;
    float4* rb4 = (float4*)rowbuf;
    #pragma unroll
    for (int i = 0; i < K_DIM / 4 / 256; ++i)
        rb4[i * 256 + tid] = make_float4(0.f, 0.f, 0.f, 0.f);
    __syncthreads();
    int n = (int)fill[row];
    if (n > CAP) n = CAP;
    const unsigned* seg = bins + (size_t)row * CAP;
    for (int i = tid; i < n; i += 256) {
        unsigned u = seg[i];
        atomicAdd(&rowbuf[u >> 16], __uint_as_float((u & 0xffffu) << 16));
    }
    unsigned ocnt = *ovf_cnt;          // ~always 0
    if (ocnt) {
        if (ocnt > OVF_CAP) ocnt = OVF_CAP;
        for (unsigned i = tid; i < ocnt; i += 256) {
            uint2 e = ovf[i];
            if ((int)(e.x >> 13) == row)   // K_DIM = 8192 = 2^13
                atomicAdd(&rowbuf[e.x & (K_DIM - 1)],
                          __uint_as_float((e.y & 0xffffu) << 16));
        }
    }
    __syncthreads();
    unsigned* Wrow = (unsigned*)(W + (size_t)row * K_DIM);  // 4096 dwords
    #pragma unroll
    for (int i = 0; i < K_DIM / 2 / 256; ++i) {
        int j = i * 256 + tid;
        unsigned pa = f32_to_bf16_rne(rowbuf[2 * j]);
        unsigned pb = f32_to_bf16_rne(rowbuf[2 * j + 1]);
        Wrow[j] = pa | (pb << 16);
    }
}

// ---------------- zero d_out fallback (ws too small diagnostic) ----------------
__global__ void zero_out_kernel(float* __restrict__ p, int n) {
    int i = blockIdx.x * blockDim.x + threadIdx.x;
    int stride = gridDim.x * blockDim.x;
    for (; i < n; i += stride) p[i] = 0.f;
}

// ---------------- bf16 NT GEMM, 256x256 8-phase (T2+T3+T4+T5) ----------------
// EXACT r6 schedule (measured 437-440 us, 1259 TF, MfmaUtil 55-56,
// conflicts 0).  Three structural variants all regressed and are closed:
//   r4/r5 32x32x16 frags   -> intrinsic 4 cyc/b128 read penalty (485 us)
//   r7 full fragment hoist -> defeated per-phase counted waits (643 us)
//   r9 (ksub,mh) phases    -> added lgkm serialization points (460 us)
// C[M][N] = A[M][K] * B[N][K]^T.  BM=BN=256, BK=64, 8 waves (2M x 4N),
// per-wave output 128x64 (acc[8][4] f32x4).  LDS 128 KiB double-buffered.
// Per K-tile: 4 phases {ds_read subtile | stage 1 half-tile | barrier |
// lgkmcnt(0) | setprio(1) 16 MFMA setprio(0) | (boundary vmcnt) | barrier};
// vmcnt(4) only at tile boundaries.  Staging liveness:
//   q0: A(t+1) h0 -> db^1   q1: A(t+1) h1 -> db^1
//   q2: B(t+2) h0 -> db     q3: B(t+2) h1 -> db   (B[db] dead after q0)
// LDS swizzle (T2, rule #21): slot (row,c) holds global k-chunk c^(row&7);
// staging pre-swizzles the global source, reads apply the same involution.
__global__ __launch_bounds__(512, 2) void gemm_bt(const ushort* __restrict__ A,
                                                  const ushort* __restrict__ B,
                                                  float* __restrict__ C) {
    constexpr int BK = 64;
    constexpr int NT = K_DIM / BK;     // 128 K-tiles
    __shared__ ushort lds[65536];      // 128 KiB

    const int nbn = N_DIM / 256;       // 32
    const int bm = blockIdx.x / nbn;
    const int bn = blockIdx.x % nbn;
    const int brow = bm * 256, bcol = bn * 256;

    const int t    = threadIdx.x;
    const int lane = t & 63;
    const int wid  = t >> 6;           // 0..7
    const int wm   = wid >> 2;         // 0..1 (M)
    const int wn   = wid & 3;          // 0..3 (N)
    const int lrow = lane & 15;
    const int ghi  = lane >> 4;        // 0..3

    const int c0 = (0 + ghi) ^ (lrow & 7);   // ksub 0
    const int c1 = (4 + ghi) ^ (lrow & 7);   // ksub 1

    f32x4  acc[8][4] = {};
    bf16x8 bfr[4][2];                  // B frags, live across one tile

    auto stage_half = [&](int db, int op, int half, int ktile) {
        const ushort* G = (op == 0) ? A : B;
        const int rbase = ((op == 0) ? brow : bcol) + half * 128;
        #pragma unroll
        for (int i = 0; i < 2; ++i) {
            int fl  = i * 512 + t;                 // 0..1023
            int row = fl >> 3;
            int cc  = (fl & 7) ^ (row & 7);
            const ushort* src = G + (size_t)(rbase + row) * K_DIM + ktile * BK + cc * 8;
            __builtin_amdgcn_global_load_lds(
                (const __attribute__((address_space(1))) void*)src,
                (__attribute__((address_space(3))) void*)
                    (&lds[db * 32768 + op * 16384 + half * 8192 + fl * 8]),
                16, 0, 0);
        }
    };

    auto tile_body = [&](int tt, int db, bool stgA, bool stgB, int vm) {
        const ushort* Ah = &lds[db * 32768 + wm * 8192];
        const ushort* Bh = &lds[db * 32768 + 16384 + (wn >> 1) * 8192 + (wn & 1) * 4096];
        const ushort* a0 = Ah + lrow * 64 + c0 * 8;
        const ushort* a1 = Ah + lrow * 64 + c1 * 8;
        const ushort* b0 = Bh + lrow * 64 + c0 * 8;
        const ushort* b1 = Bh + lrow * 64 + c1 * 8;
        #pragma unroll
        for (int q = 0; q < 4; ++q) {
            bf16x8 af[2][2];
            if (q == 0) {
                #pragma unroll
                for (int n = 0; n < 4; ++n) {
                    bfr[n][0] = *(const bf16x8*)(b0 + n * 1024);
                    bfr[n][1] = *(const bf16x8*)(b1 + n * 1024);
                }
            }
            #pragma unroll
            for (int j = 0; j < 2; ++j) {
                af[j][0] = *(const bf16x8*)(a0 + (2 * q + j) * 1024);
                af[j][1] = *(const bf16x8*)(a1 + (2 * q + j) * 1024);
            }
            if (q == 0 && stgA) stage_half(db ^ 1, 0, 0, tt + 1);
            if (q == 1 && stgA) stage_half(db ^ 1, 0, 1, tt + 1);
            if (q == 2 && stgB) stage_half(db,     1, 0, tt + 2);
            if (q == 3 && stgB) stage_half(db,     1, 1, tt + 2);
            __builtin_amdgcn_s_barrier();
            asm volatile("s_waitcnt lgkmcnt(0)" ::: "memory");
            __builtin_amdgcn_s_setprio(1);
            #pragma unroll
            for (int j = 0; j < 2; ++j)
                #pragma unroll
                for (int n = 0; n < 4; ++n) {
                    acc[2 * q + j][n] = __builtin_amdgcn_mfma_f32_16x16x32_bf16(
                        af[j][0], bfr[n][0], acc[2 * q + j][n], 0, 0, 0);
                    acc[2 * q + j][n] = __builtin_amdgcn_mfma_f32_16x16x32_bf16(
                        af[j][1], bfr[n][1], acc[2 * q + j][n], 0, 0, 0);
                }
            __builtin_amdgcn_s_setprio(0);
            if (q == 3) {
                if (vm == 4) asm volatile("s_waitcnt vmcnt(4)" ::: "memory");
                else         asm volatile("s_waitcnt vmcnt(0)" ::: "memory");
            }
            __builtin_amdgcn_s_barrier();
        }
    };

    // ---- prologue: tile 0 fully + B(1); drain to 4 (B(1) stays in flight) ----
    stage_half(0, 0, 0, 0);
    stage_half(0, 0, 1, 0);
    stage_half(0, 1, 0, 0);
    stage_half(0, 1, 1, 0);
    stage_half(1, 1, 0, 1);
    stage_half(1, 1, 1, 1);
    asm volatile("s_waitcnt vmcnt(4)" ::: "memory");
    __builtin_amdgcn_s_barrier();

    for (int tt = 0; tt < NT - 2; tt += 2) {
        tile_body(tt,     0, true, true, 4);
        tile_body(tt + 1, 1, true, true, 4);
    }
    tile_body(NT - 2, 0, true,  false, 0);
    tile_body(NT - 1, 1, false, false, 0);

    // ---- epilogue: C/D layout col=lane&15, row=(lane>>4)*4+r ----
    const int crow0 = brow + wm * 128;
    const int ccol0 = bcol + wn * 64;
    #pragma unroll
    for (int m = 0; m < 8; ++m) {
        #pragma unroll
        for (int n = 0; n < 4; ++n) {
            int col   = ccol0 + n * 16 + lrow;
            int rbase = crow0 + m * 16 + (lane >> 4) * 4;
            #pragma unroll
            for (int r = 0; r < 4; ++r)
                C[(size_t)(rbase + r) * N_DIM + col] = acc[m][n][r];
        }
    }
}

extern "C" void kernel_launch(void* const* d_in, const int* in_sizes, int n_in,
                              void* d_out, int out_size, void* d_ws, size_t ws_size,
                              hipStream_t stream) {
    const float* x    = (const float*)d_in[0];
    const float* vals = (const float*)d_in[1];
    const int* rows   = (const int*)d_in[2];
    const int* cols   = (const int*)d_in[3];
    float* out        = (float*)d_out;
    const int n_items = in_sizes[1];

    const size_t W_BF16_BYTES = (size_t)N_DIM * K_DIM * 2;        // 128 MiB
    const size_t X_BF16_BYTES = (size_t)M_DIM * K_DIM * 2;        //  64 MiB
    const size_t BINS_BYTES   = (size_t)N_DIM * CAP * 4;          //  24 MiB
    const size_t FILL_BYTES   = (size_t)N_DIM * 4;                //  32 KiB
    const size_t OVF_BYTES    = 16 + (size_t)OVF_CAP * 8;
    const size_t NEEDED = W_BF16_BYTES + X_BF16_BYTES + BINS_BYTES
                        + FILL_BYTES + OVF_BYTES;

    if (ws_size < NEEDED) {
        // Diagnostic fallback: clean absmax=126 failure signals ws too small.
        zero_out_kernel<<<2048, 256, 0, stream>>>(out, out_size);
        return;
    }

    char* ws = (char*)d_ws;
    unsigned short* Wb = (unsigned short*)ws;
    ushort*   Xb      = (ushort*)(ws + W_BF16_BYTES);
    unsigned* bins    = (unsigned*)(ws + W_BF16_BYTES + X_BF16_BYTES);
    unsigned* fill    = (unsigned*)(ws + W_BF16_BYTES + X_BF16_BYTES + BINS_BYTES);
    unsigned* ovf_cnt = fill + N_DIM;
    uint2*    ovf     = (uint2*)(ovf_cnt + 4);

    // 1) zero fill counters + ovf_cnt (stream memset: graph-capturable)
    hipMemsetAsync(fill, 0, FILL_BYTES + 16, stream);
    // 2) fused: cast x to bf16 || bin items by destination row
    const int reorder_blocks = (n_items / 2 + 255) / 256;
    cvt_reorder_kernel<<<CVT_BLOCKS + reorder_blocks, 256, 0, stream>>>(
        (const float4*)x, (ushort4*)Xb, (M_DIM * K_DIM) / 4,
        vals, rows, cols, bins, fill, ovf_cnt, ovf, n_items);
    // 3) per-row accumulate in f32 LDS + merge overflow + write bf16 W
    row_accum_kernel<<<N_DIM, 256, 0, stream>>>(bins, fill, ovf_cnt, ovf, Wb);
    // 4) GEMM: out = Xb (M x K) * Wb (N x K)^T
    gemm_bt<<<(M_DIM / 256) * (N_DIM / 256), 512, 0, stream>>>(
        Xb, (const ushort*)Wb, out);
}

// Round 11
// 579.955 us; speedup vs baseline: 1.0861x; 1.0194x over previous
//
#include <hip/hip_runtime.h>
#include <hip/hip_bf16.h>

#define M_DIM 4096
#define N_DIM 8192
#define K_DIM 8192
#define CAP   768          // bin capacity per W row (mean 488, sigma 22)
#define OVF_CAP 4096

using bf16x8 = __attribute__((ext_vector_type(8))) short;
using f32x4  = __attribute__((ext_vector_type(4))) float;

static __device__ __forceinline__ unsigned short f32_to_bf16_rne(float f) {
    unsigned u = __float_as_uint(f);
    unsigned rounding = 0x7FFFu + ((u >> 16) & 1u);
    u += rounding;
    return (unsigned short)(u >> 16);
}

// ---------------- fused pass 1: cvt x -> bf16  ||  bin items by row -------
// r10 fix: roles interleaved by bid PARITY (even = cast, odd = bin) so both
// populations are co-resident from the first dispatch wave -- r9's
// block-range split dispatched all cast blocks first, serializing the
// "overlap".  Binning is 4 items/thread (int4/float4 loads, independent
// atomic chains = 4x MLP).  bins[row][pos] = (col<<16)|bf16(val), pos via
// device-scope atomicAdd on fill[row] (8192 hot counters).  Overflow
// (>=13 sigma, ~impossible) goes to a list merged by row_accum.
__global__ void cvt_reorder_kernel(const float4* __restrict__ xsrc,
                                   ushort4* __restrict__ xdst, int xn4,
                                   const float* __restrict__ vals,
                                   const int* __restrict__ rows,
                                   const int* __restrict__ cols,
                                   unsigned* __restrict__ bins,
                                   unsigned* __restrict__ fill,
                                   unsigned* __restrict__ ovf_cnt,
                                   uint2* __restrict__ ovf, int n) {
    const int half = (int)gridDim.x >> 1;
    const int bi   = blockIdx.x >> 1;
    if ((blockIdx.x & 1) == 0) {
        // ---- cast role: grid-stride over x ----
        int i = bi * blockDim.x + threadIdx.x;
        int stride = half * blockDim.x;
        for (; i < xn4; i += stride) {
            float4 v = xsrc[i];
            ushort4 o;
            o.x = f32_to_bf16_rne(v.x);
            o.y = f32_to_bf16_rne(v.y);
            o.z = f32_to_bf16_rne(v.z);
            o.w = f32_to_bf16_rne(v.w);
            xdst[i] = o;
        }
        return;
    }
    // ---- binning role: 4 items/thread ----
    int i = (bi * blockDim.x + threadIdx.x) * 4;
    if (i >= n) return;
    const int m = n - i;               // >= 1; full int4 load safe (i % 4 == 0)
    int4   r4 = *(const int4*)(rows + i);
    int4   c4 = *(const int4*)(cols + i);
    float4 v4 = *(const float4*)(vals + i);
    const int   ra[4] = {r4.x, r4.y, r4.z, r4.w};
    const int   ca[4] = {c4.x, c4.y, c4.z, c4.w};
    const float va[4] = {v4.x, v4.y, v4.z, v4.w};
    #pragma unroll
    for (int j = 0; j < 4; ++j) {
        if (j >= m) break;
        int r = ra[j], c = ca[j];
        unsigned h = f32_to_bf16_rne(va[j]);
        unsigned pos = atomicAdd(&fill[r], 1u);
        if (pos < CAP) {
            bins[(size_t)r * CAP + pos] = ((unsigned)c << 16) | h;
        } else {
            unsigned o = atomicAdd(ovf_cnt, 1u);
            if (o < OVF_CAP)
                ovf[o] = make_uint2((unsigned)r * K_DIM + (unsigned)c, h);
        }
    }
}

// ---------------- pass 2: per-row accumulate + write full bf16 row --------
// One block per W row: f32 LDS rowbuf (32 KB), LDS atomics for ~488 items,
// merge any overflow entries for this row (f32, pre-rounding), then one
// coalesced 16 KB row write.  Replaces the W-zero pass, the global atomic
// scatter, AND a separate ovf_apply launch.
__global__ __launch_bounds__(256) void row_accum_kernel(
        const unsigned* __restrict__ bins,
        const unsigned* __restrict__ fill,
        const unsigned* __restrict__ ovf_cnt,
        const uint2* __restrict__ ovf,
        unsigned short* __restrict__ W) {
    __shared__ float rowbuf[K_DIM];    // 32 KB
    const int row = blockIdx.x;
    const int tid = threadIdx.x;
    float4* rb4 = (float4*)rowbuf;
    #pragma unroll
    for (int i = 0; i < K_DIM / 4 / 256; ++i)
        rb4[i * 256 + tid] = make_float4(0.f, 0.f, 0.f, 0.f);
    __syncthreads();
    int n = (int)fill[row];
    if (n > CAP) n = CAP;
    const unsigned* seg = bins + (size_t)row * CAP;
    for (int i = tid; i < n; i += 256) {
        unsigned u = seg[i];
        atomicAdd(&rowbuf[u >> 16], __uint_as_float((u & 0xffffu) << 16));
    }
    unsigned ocnt = *ovf_cnt;          // ~always 0
    if (ocnt) {
        if (ocnt > OVF_CAP) ocnt = OVF_CAP;
        for (unsigned i = tid; i < ocnt; i += 256) {
            uint2 e = ovf[i];
            if ((int)(e.x >> 13) == row)   // K_DIM = 8192 = 2^13
                atomicAdd(&rowbuf[e.x & (K_DIM - 1)],
                          __uint_as_float((e.y & 0xffffu) << 16));
        }
    }
    __syncthreads();
    unsigned* Wrow = (unsigned*)(W + (size_t)row * K_DIM);  // 4096 dwords
    #pragma unroll
    for (int i = 0; i < K_DIM / 2 / 256; ++i) {
        int j = i * 256 + tid;
        unsigned pa = f32_to_bf16_rne(rowbuf[2 * j]);
        unsigned pb = f32_to_bf16_rne(rowbuf[2 * j + 1]);
        Wrow[j] = pa | (pb << 16);
    }
}

// ---------------- zero d_out fallback (ws too small diagnostic) ----------------
__global__ void zero_out_kernel(float* __restrict__ p, int n) {
    int i = blockIdx.x * blockDim.x + threadIdx.x;
    int stride = gridDim.x * blockDim.x;
    for (; i < n; i += stride) p[i] = 0.f;
}

// ---------------- bf16 NT GEMM, 256x256 8-phase (T2+T3+T4+T5) ----------------
// EXACT r6 schedule (measured 425-440 us, ~1280 TF, MfmaUtil 56-57,
// conflicts 0).  Structural variants all regressed and are closed:
//   r4/r5 32x32x16 frags   -> intrinsic 4 cyc/b128 read penalty (485 us)
//   r7 full fragment hoist -> defeated per-phase counted waits (643 us)
//   r9 (ksub,mh) phases    -> added lgkm serialization points (460 us)
// C[M][N] = A[M][K] * B[N][K]^T.  BM=BN=256, BK=64, 8 waves (2M x 4N),
// per-wave output 128x64 (acc[8][4] f32x4).  LDS 128 KiB double-buffered.
// Per K-tile: 4 phases {ds_read subtile | stage 1 half-tile | barrier |
// lgkmcnt(0) | setprio(1) 16 MFMA setprio(0) | (boundary vmcnt) | barrier};
// vmcnt(4) only at tile boundaries.  Staging liveness:
//   q0: A(t+1) h0 -> db^1   q1: A(t+1) h1 -> db^1
//   q2: B(t+2) h0 -> db     q3: B(t+2) h1 -> db   (B[db] dead after q0)
// LDS swizzle (T2, rule #21): slot (row,c) holds global k-chunk c^(row&7);
// staging pre-swizzles the global source, reads apply the same involution.
__global__ __launch_bounds__(512, 2) void gemm_bt(const ushort* __restrict__ A,
                                                  const ushort* __restrict__ B,
                                                  float* __restrict__ C) {
    constexpr int BK = 64;
    constexpr int NT = K_DIM / BK;     // 128 K-tiles
    __shared__ ushort lds[65536];      // 128 KiB

    const int nbn = N_DIM / 256;       // 32
    const int bm = blockIdx.x / nbn;
    const int bn = blockIdx.x % nbn;
    const int brow = bm * 256, bcol = bn * 256;

    const int t    = threadIdx.x;
    const int lane = t & 63;
    const int wid  = t >> 6;           // 0..7
    const int wm   = wid >> 2;         // 0..1 (M)
    const int wn   = wid & 3;          // 0..3 (N)
    const int lrow = lane & 15;
    const int ghi  = lane >> 4;        // 0..3

    const int c0 = (0 + ghi) ^ (lrow & 7);   // ksub 0
    const int c1 = (4 + ghi) ^ (lrow & 7);   // ksub 1

    f32x4  acc[8][4] = {};
    bf16x8 bfr[4][2];                  // B frags, live across one tile

    auto stage_half = [&](int db, int op, int half, int ktile) {
        const ushort* G = (op == 0) ? A : B;
        const int rbase = ((op == 0) ? brow : bcol) + half * 128;
        #pragma unroll
        for (int i = 0; i < 2; ++i) {
            int fl  = i * 512 + t;                 // 0..1023
            int row = fl >> 3;
            int cc  = (fl & 7) ^ (row & 7);
            const ushort* src = G + (size_t)(rbase + row) * K_DIM + ktile * BK + cc * 8;
            __builtin_amdgcn_global_load_lds(
                (const __attribute__((address_space(1))) void*)src,
                (__attribute__((address_space(3))) void*)
                    (&lds[db * 32768 + op * 16384 + half * 8192 + fl * 8]),
                16, 0, 0);
        }
    };

    auto tile_body = [&](int tt, int db, bool stgA, bool stgB, int vm) {
        const ushort* Ah = &lds[db * 32768 + wm * 8192];
        const ushort* Bh = &lds[db * 32768 + 16384 + (wn >> 1) * 8192 + (wn & 1) * 4096];
        const ushort* a0 = Ah + lrow * 64 + c0 * 8;
        const ushort* a1 = Ah + lrow * 64 + c1 * 8;
        const ushort* b0 = Bh + lrow * 64 + c0 * 8;
        const ushort* b1 = Bh + lrow * 64 + c1 * 8;
        #pragma unroll
        for (int q = 0; q < 4; ++q) {
            bf16x8 af[2][2];
            if (q == 0) {
                #pragma unroll
                for (int n = 0; n < 4; ++n) {
                    bfr[n][0] = *(const bf16x8*)(b0 + n * 1024);
                    bfr[n][1] = *(const bf16x8*)(b1 + n * 1024);
                }
            }
            #pragma unroll
            for (int j = 0; j < 2; ++j) {
                af[j][0] = *(const bf16x8*)(a0 + (2 * q + j) * 1024);
                af[j][1] = *(const bf16x8*)(a1 + (2 * q + j) * 1024);
            }
            if (q == 0 && stgA) stage_half(db ^ 1, 0, 0, tt + 1);
            if (q == 1 && stgA) stage_half(db ^ 1, 0, 1, tt + 1);
            if (q == 2 && stgB) stage_half(db,     1, 0, tt + 2);
            if (q == 3 && stgB) stage_half(db,     1, 1, tt + 2);
            __builtin_amdgcn_s_barrier();
            asm volatile("s_waitcnt lgkmcnt(0)" ::: "memory");
            __builtin_amdgcn_s_setprio(1);
            #pragma unroll
            for (int j = 0; j < 2; ++j)
                #pragma unroll
                for (int n = 0; n < 4; ++n) {
                    acc[2 * q + j][n] = __builtin_amdgcn_mfma_f32_16x16x32_bf16(
                        af[j][0], bfr[n][0], acc[2 * q + j][n], 0, 0, 0);
                    acc[2 * q + j][n] = __builtin_amdgcn_mfma_f32_16x16x32_bf16(
                        af[j][1], bfr[n][1], acc[2 * q + j][n], 0, 0, 0);
                }
            __builtin_amdgcn_s_setprio(0);
            if (q == 3) {
                if (vm == 4) asm volatile("s_waitcnt vmcnt(4)" ::: "memory");
                else         asm volatile("s_waitcnt vmcnt(0)" ::: "memory");
            }
            __builtin_amdgcn_s_barrier();
        }
    };

    // ---- prologue: tile 0 fully + B(1); drain to 4 (B(1) stays in flight) ----
    stage_half(0, 0, 0, 0);
    stage_half(0, 0, 1, 0);
    stage_half(0, 1, 0, 0);
    stage_half(0, 1, 1, 0);
    stage_half(1, 1, 0, 1);
    stage_half(1, 1, 1, 1);
    asm volatile("s_waitcnt vmcnt(4)" ::: "memory");
    __builtin_amdgcn_s_barrier();

    for (int tt = 0; tt < NT - 2; tt += 2) {
        tile_body(tt,     0, true, true, 4);
        tile_body(tt + 1, 1, true, true, 4);
    }
    tile_body(NT - 2, 0, true,  false, 0);
    tile_body(NT - 1, 1, false, false, 0);

    // ---- epilogue: C/D layout col=lane&15, row=(lane>>4)*4+r ----
    const int crow0 = brow + wm * 128;
    const int ccol0 = bcol + wn * 64;
    #pragma unroll
    for (int m = 0; m < 8; ++m) {
        #pragma unroll
        for (int n = 0; n < 4; ++n) {
            int col   = ccol0 + n * 16 + lrow;
            int rbase = crow0 + m * 16 + (lane >> 4) * 4;
            #pragma unroll
            for (int r = 0; r < 4; ++r)
                C[(size_t)(rbase + r) * N_DIM + col] = acc[m][n][r];
        }
    }
}

extern "C" void kernel_launch(void* const* d_in, const int* in_sizes, int n_in,
                              void* d_out, int out_size, void* d_ws, size_t ws_size,
                              hipStream_t stream) {
    const float* x    = (const float*)d_in[0];
    const float* vals = (const float*)d_in[1];
    const int* rows   = (const int*)d_in[2];
    const int* cols   = (const int*)d_in[3];
    float* out        = (float*)d_out;
    const int n_items = in_sizes[1];

    const size_t W_BF16_BYTES = (size_t)N_DIM * K_DIM * 2;        // 128 MiB
    const size_t X_BF16_BYTES = (size_t)M_DIM * K_DIM * 2;        //  64 MiB
    const size_t BINS_BYTES   = (size_t)N_DIM * CAP * 4;          //  24 MiB
    const size_t FILL_BYTES   = (size_t)N_DIM * 4;                //  32 KiB
    const size_t OVF_BYTES    = 16 + (size_t)OVF_CAP * 8;
    const size_t NEEDED = W_BF16_BYTES + X_BF16_BYTES + BINS_BYTES
                        + FILL_BYTES + OVF_BYTES;

    if (ws_size < NEEDED) {
        // Diagnostic fallback: clean absmax=126 failure signals ws too small.
        zero_out_kernel<<<2048, 256, 0, stream>>>(out, out_size);
        return;
    }

    char* ws = (char*)d_ws;
    unsigned short* Wb = (unsigned short*)ws;
    ushort*   Xb      = (ushort*)(ws + W_BF16_BYTES);
    unsigned* bins    = (unsigned*)(ws + W_BF16_BYTES + X_BF16_BYTES);
    unsigned* fill    = (unsigned*)(ws + W_BF16_BYTES + X_BF16_BYTES + BINS_BYTES);
    unsigned* ovf_cnt = fill + N_DIM;
    uint2*    ovf     = (uint2*)(ovf_cnt + 4);

    // 1) zero fill counters + ovf_cnt (stream memset: graph-capturable)
    hipMemsetAsync(fill, 0, FILL_BYTES + 16, stream);
    // 2) fused: cast x to bf16 (even bids) || bin items 4/thread (odd bids)
    const int reorder_blocks = (n_items / 4 + 255) / 256;   // 3907
    cvt_reorder_kernel<<<2 * reorder_blocks, 256, 0, stream>>>(
        (const float4*)x, (ushort4*)Xb, (M_DIM * K_DIM) / 4,
        vals, rows, cols, bins, fill, ovf_cnt, ovf, n_items);
    // 3) per-row accumulate in f32 LDS + merge overflow + write bf16 W
    row_accum_kernel<<<N_DIM, 256, 0, stream>>>(bins, fill, ovf_cnt, ovf, Wb);
    // 4) GEMM: out = Xb (M x K) * Wb (N x K)^T
    gemm_bt<<<(M_DIM / 256) * (N_DIM / 256), 512, 0, stream>>>(
        Xb, (const ushort*)Wb, out);
}